// Round 1
// baseline (575.025 us; speedup 1.0000x reference)
//
#include <hip/hip_runtime.h>
#include <hip/hip_bf16.h>

// Problem constants (from reference): H=128, A=8, D=16. N, E read from in_sizes.
#define HDIM 128

// ---------------------------------------------------------------------------
// zero int array (deg + cursor)
__global__ void zero_kernel(int* __restrict__ p, int n) {
    int i = blockIdx.x * blockDim.x + threadIdx.x;
    if (i < n) p[i] = 0;
}

// ---------------------------------------------------------------------------
// Per-node projections: Qn = q @ Wq.T + bq, etc.  Tiled f32 GEMM.
// Grid: ceil(N/64) blocks x 256 threads. Each block: 64 nodes x 128 cols,
// thread (cg=tid&31, ng=tid>>5) computes cols 4cg..4cg+3 for nodes 8ng..8ng+7.
// x tile staged in LDS (32KB); xs reads are wave-uniform per ng -> broadcast.
__global__ void proj3_kernel(const float* __restrict__ qin, const float* __restrict__ kin,
                             const float* __restrict__ vin,
                             const float* __restrict__ Wq, const float* __restrict__ bq,
                             const float* __restrict__ Wk, const float* __restrict__ bk,
                             const float* __restrict__ Wv, const float* __restrict__ bv,
                             float* __restrict__ Qo, float* __restrict__ Ko,
                             float* __restrict__ Vo, int n)
{
    __shared__ float xs[64][HDIM];            // 32 KB
    const int tid = threadIdx.x;
    const int cg  = tid & 31;                 // col group: cols 4cg..4cg+3
    const int ng  = tid >> 5;                 // node group: nodes 8ng..8ng+7
    const long node0 = (long)blockIdx.x * 64;

    const float* xin[3] = {qin, kin, vin};
    const float* Wm[3]  = {Wq, Wk, Wv};
    const float* bm[3]  = {bq, bk, bv};
    float*       om[3]  = {Qo, Ko, Vo};

    for (int m = 0; m < 3; ++m) {
        const float* x = xin[m];
        __syncthreads();                      // protect xs from previous matrix readers
        // stage 64x128 tile: 2048 float4 slots, 8 per thread, coalesced
        for (int it = 0; it < 8; ++it) {
            int slot = it * 256 + tid;        // 0..2047
            int row  = slot >> 5;             // 32 float4 per row
            int c4   = slot & 31;
            long node = node0 + row;
            float4 val = make_float4(0.f, 0.f, 0.f, 0.f);
            if (node < n) val = ((const float4*)(x + node * HDIM))[c4];
            ((float4*)&xs[row][0])[c4] = val;
        }
        __syncthreads();

        float acc[4][8];
        #pragma unroll
        for (int c = 0; c < 4; ++c)
            #pragma unroll
            for (int t = 0; t < 8; ++t) acc[c][t] = 0.f;

        const float* W = Wm[m];
        const float4* W0 = (const float4*)(W + (size_t)(4 * cg + 0) * HDIM);
        const float4* W1 = (const float4*)(W + (size_t)(4 * cg + 1) * HDIM);
        const float4* W2 = (const float4*)(W + (size_t)(4 * cg + 2) * HDIM);
        const float4* W3 = (const float4*)(W + (size_t)(4 * cg + 3) * HDIM);

        for (int i4 = 0; i4 < 32; ++i4) {
            float4 w0 = W0[i4];
            float4 w1 = W1[i4];
            float4 w2 = W2[i4];
            float4 w3 = W3[i4];
            #pragma unroll
            for (int t = 0; t < 8; ++t) {
                float4 xv = ((const float4*)&xs[ng * 8 + t][0])[i4];   // LDS broadcast
                acc[0][t] += w0.x * xv.x + w0.y * xv.y + w0.z * xv.z + w0.w * xv.w;
                acc[1][t] += w1.x * xv.x + w1.y * xv.y + w1.z * xv.z + w1.w * xv.w;
                acc[2][t] += w2.x * xv.x + w2.y * xv.y + w2.z * xv.z + w2.w * xv.w;
                acc[3][t] += w3.x * xv.x + w3.y * xv.y + w3.z * xv.z + w3.w * xv.w;
            }
        }

        float4 bb = ((const float4*)bm[m])[cg];
        float* o = om[m];
        #pragma unroll
        for (int t = 0; t < 8; ++t) {
            long node = node0 + ng * 8 + t;
            if (node < n) {
                float4 r;
                r.x = acc[0][t] + bb.x;
                r.y = acc[1][t] + bb.y;
                r.z = acc[2][t] + bb.z;
                r.w = acc[3][t] + bb.w;
                ((float4*)(o + node * HDIM))[cg] = r;
            }
        }
    }
}

// ---------------------------------------------------------------------------
// degree count per destination node
__global__ void deg_kernel(const int* __restrict__ qidx, int* __restrict__ deg, int E) {
    int e = blockIdx.x * blockDim.x + threadIdx.x;
    if (e < E) atomicAdd(&deg[qidx[e]], 1);
}

// single-block exclusive scan (N=50000): wave shfl-scan + serial wave-base pass
__global__ void scan_kernel(const int* __restrict__ deg, int* __restrict__ offs, int n) {
    __shared__ int wsum[16];
    __shared__ int s_running;
    const int lane = threadIdx.x & 63;
    const int wv   = threadIdx.x >> 6;
    if (threadIdx.x == 0) s_running = 0;
    __syncthreads();
    const int nch = (n + 1023) / 1024;
    for (int c = 0; c < nch; ++c) {
        int i = c * 1024 + (int)threadIdx.x;
        int v = (i < n) ? deg[i] : 0;
        int sc = v;
        #pragma unroll
        for (int d = 1; d < 64; d <<= 1) {
            int t = __shfl_up(sc, d, 64);
            if (lane >= d) sc += t;
        }
        if (lane == 63) wsum[wv] = sc;
        __syncthreads();
        if (threadIdx.x == 0) {
            int base = s_running;
            #pragma unroll
            for (int w = 0; w < 16; ++w) { int t = wsum[w]; wsum[w] = base; base += t; }
            s_running = base;
        }
        __syncthreads();
        if (i < n) offs[i] = wsum[wv] + (sc - v);
        __syncthreads();                       // wsum reused next chunk
    }
    if (threadIdx.x == 0) offs[n] = s_running;
}

// scatter edge ids into per-destination CSR buckets
__global__ void fill_kernel(const int* __restrict__ qidx, const int* __restrict__ offs,
                            int* __restrict__ cursor, int* __restrict__ elist, int E) {
    int e = blockIdx.x * blockDim.x + threadIdx.x;
    if (e < E) {
        int d = qidx[e];
        int pos = offs[d] + atomicAdd(&cursor[d], 1);
        elist[pos] = e;
    }
}

// ---------------------------------------------------------------------------
// Aggregation: one wave per destination node. Lane l owns dims 2l,2l+1;
// head a = l>>3 reduces its D=16 dot via 3 shfl_xor steps within 8 lanes.
__global__ void agg_kernel(const float* __restrict__ Qn, const float* __restrict__ Kn,
                           const float* __restrict__ Vn,
                           const int* __restrict__ kidx, const int* __restrict__ offs,
                           const int* __restrict__ elist, float* __restrict__ out, int n)
{
    const int lane = threadIdx.x & 63;
    const int wid  = threadIdx.x >> 6;
    const int node = blockIdx.x * 4 + wid;
    if (node >= n) return;

    const float2 qv = *(const float2*)&Qn[(size_t)node * HDIM + lane * 2];

    float acc0 = 0.f, acc1 = 0.f, dsum = 0.f;
    const int beg = offs[node], end = offs[node + 1];
    for (int p = beg; p < end; ++p) {
        int e   = elist[p];
        int src = kidx[e];
        const float2 kv = *(const float2*)&Kn[(size_t)src * HDIM + lane * 2];
        const float2 vv = *(const float2*)&Vn[(size_t)src * HDIM + lane * 2];
        float part = qv.x * kv.x + qv.y * kv.y;
        part += __shfl_xor(part, 1, 64);
        part += __shfl_xor(part, 2, 64);
        part += __shfl_xor(part, 4, 64);       // all 8 lanes of head now hold full dot
        float w = __expf(part * 0.25f);        // 1/sqrt(D)=0.25, plain exp per reference
        dsum += w;
        acc0 += w * vv.x;
        acc1 += w * vv.y;
    }
    float inv = 1.f / dsum;                    // deg>=1 guaranteed (identity edges)
    *(float2*)&out[(size_t)node * HDIM + lane * 2] = make_float2(acc0 * inv, acc1 * inv);
}

// ---------------------------------------------------------------------------
extern "C" void kernel_launch(void* const* d_in, const int* in_sizes, int n_in,
                              void* d_out, int out_size, void* d_ws, size_t ws_size,
                              hipStream_t stream) {
    const float* q  = (const float*)d_in[0];
    const float* k  = (const float*)d_in[1];
    const float* v  = (const float*)d_in[2];
    const float* Wq = (const float*)d_in[3];
    const float* bq = (const float*)d_in[4];
    const float* Wk = (const float*)d_in[5];
    const float* bk = (const float*)d_in[6];
    const float* Wv = (const float*)d_in[7];
    const float* bv = (const float*)d_in[8];
    const int* qidx = (const int*)d_in[9];
    const int* kidx = (const int*)d_in[10];
    float* out = (float*)d_out;

    const int N = in_sizes[0] / HDIM;
    const int E = in_sizes[9];

    char* p = (char*)d_ws;
    float* Qn = (float*)p; p += (size_t)N * HDIM * sizeof(float);
    float* Kn = (float*)p; p += (size_t)N * HDIM * sizeof(float);
    float* Vn = (float*)p; p += (size_t)N * HDIM * sizeof(float);
    int* deg    = (int*)p; p += (size_t)N * sizeof(int);
    int* cursor = (int*)p; p += (size_t)N * sizeof(int);   // contiguous with deg
    int* offs   = (int*)p; p += (size_t)(N + 1) * sizeof(int);
    int* elist  = (int*)p; p += (size_t)E * sizeof(int);

    zero_kernel<<<(2 * N + 255) / 256, 256, 0, stream>>>(deg, 2 * N);
    proj3_kernel<<<(N + 63) / 64, 256, 0, stream>>>(q, k, v, Wq, bq, Wk, bk, Wv, bv,
                                                    Qn, Kn, Vn, N);
    deg_kernel<<<(E + 255) / 256, 256, 0, stream>>>(qidx, deg, E);
    scan_kernel<<<1, 1024, 0, stream>>>(deg, offs, N);
    fill_kernel<<<(E + 255) / 256, 256, 0, stream>>>(qidx, offs, cursor, elist, E);
    agg_kernel<<<(N + 3) / 4, 256, 0, stream>>>(Qn, Kn, Vn, kidx, offs, elist, out, N);
}

// Round 3
// 439.184 us; speedup vs baseline: 1.3093x; 1.3093x over previous
//
#include <hip/hip_runtime.h>
#include <hip/hip_bf16.h>

#define HDIM 128

// ---------------------------------------------------------------------------
__global__ void zero_kernel(int* __restrict__ p, int n) {
    int i = blockIdx.x * blockDim.x + threadIdx.x;
    if (i < n) p[i] = 0;
}

// ---------------------------------------------------------------------------
// bf16 helpers
__device__ inline unsigned pack_bf16x2(float a, float b) {
    __hip_bfloat16 ha = __float2bfloat16(a);
    __hip_bfloat16 hb = __float2bfloat16(b);
    unsigned ua = (unsigned)__builtin_bit_cast(unsigned short, ha);
    unsigned ub = (unsigned)__builtin_bit_cast(unsigned short, hb);
    return ua | (ub << 16);                    // low half = a (first element)
}

// ---------------------------------------------------------------------------
// Per-node projection. gridDim.y = m (0=Q fp32 out, 1=K, 2=V packed bf16 out).
// Block: 64 nodes x 128 cols, 256 threads; thread (cg,ng) -> 4 cols x 8 nodes.
// KV layout: per node 64 pairs, each pair = uint2 {K2p|K2p+1, V2p|V2p+1}.
// As uint array: KV[node*128 + 2*p + sel], sel 0=K 1=V.
__global__ void proj_kernel(const float* __restrict__ qin, const float* __restrict__ kin,
                            const float* __restrict__ vin,
                            const float* __restrict__ Wq, const float* __restrict__ bq,
                            const float* __restrict__ Wk, const float* __restrict__ bk,
                            const float* __restrict__ Wv, const float* __restrict__ bv,
                            float* __restrict__ Qo, unsigned* __restrict__ KV, int n)
{
    __shared__ float xs[64][HDIM];            // 32 KB -> 5 blocks/CU by LDS
    const int tid = threadIdx.x;
    const int cg  = tid & 31;
    const int ng  = tid >> 5;
    const long node0 = (long)blockIdx.x * 64;
    const int m = blockIdx.y;                 // block-uniform branch

    const float* x = (m == 0) ? qin : (m == 1) ? kin : vin;
    const float* W = (m == 0) ? Wq  : (m == 1) ? Wk  : Wv;
    const float* b = (m == 0) ? bq  : (m == 1) ? bk  : bv;

    // stage 64x128 x-tile, coalesced float4
    for (int it = 0; it < 8; ++it) {
        int slot = it * 256 + tid;
        int row  = slot >> 5;
        int c4   = slot & 31;
        long node = node0 + row;
        float4 val = make_float4(0.f, 0.f, 0.f, 0.f);
        if (node < n) val = ((const float4*)(x + node * HDIM))[c4];
        ((float4*)&xs[row][0])[c4] = val;
    }
    __syncthreads();

    float acc[4][8];
    #pragma unroll
    for (int c = 0; c < 4; ++c)
        #pragma unroll
        for (int t = 0; t < 8; ++t) acc[c][t] = 0.f;

    const float4* W0 = (const float4*)(W + (size_t)(4 * cg + 0) * HDIM);
    const float4* W1 = (const float4*)(W + (size_t)(4 * cg + 1) * HDIM);
    const float4* W2 = (const float4*)(W + (size_t)(4 * cg + 2) * HDIM);
    const float4* W3 = (const float4*)(W + (size_t)(4 * cg + 3) * HDIM);

    for (int i4 = 0; i4 < 32; ++i4) {
        float4 w0 = W0[i4];
        float4 w1 = W1[i4];
        float4 w2 = W2[i4];
        float4 w3 = W3[i4];
        #pragma unroll
        for (int t = 0; t < 8; ++t) {
            float4 xv = ((const float4*)&xs[ng * 8 + t][0])[i4];   // LDS broadcast
            acc[0][t] += w0.x * xv.x + w0.y * xv.y + w0.z * xv.z + w0.w * xv.w;
            acc[1][t] += w1.x * xv.x + w1.y * xv.y + w1.z * xv.z + w1.w * xv.w;
            acc[2][t] += w2.x * xv.x + w2.y * xv.y + w2.z * xv.z + w2.w * xv.w;
            acc[3][t] += w3.x * xv.x + w3.y * xv.y + w3.z * xv.z + w3.w * xv.w;
        }
    }

    float4 bb = ((const float4*)b)[cg];
    if (m == 0) {
        #pragma unroll
        for (int t = 0; t < 8; ++t) {
            long node = node0 + ng * 8 + t;
            if (node < n) {
                float4 r;
                r.x = acc[0][t] + bb.x;
                r.y = acc[1][t] + bb.y;
                r.z = acc[2][t] + bb.z;
                r.w = acc[3][t] + bb.w;
                ((float4*)(Qo + node * HDIM))[cg] = r;
            }
        }
    } else {
        const int sel = m - 1;                // 0=K, 1=V
        #pragma unroll
        for (int t = 0; t < 8; ++t) {
            long node = node0 + ng * 8 + t;
            if (node < n) {
                unsigned lo = pack_bf16x2(acc[0][t] + bb.x, acc[1][t] + bb.y); // pair 2cg
                unsigned hi = pack_bf16x2(acc[2][t] + bb.z, acc[3][t] + bb.w); // pair 2cg+1
                KV[node * 128 + 2 * (2 * cg)     + sel] = lo;
                KV[node * 128 + 2 * (2 * cg + 1) + sel] = hi;
            }
        }
    }
}

// ---------------------------------------------------------------------------
__global__ void deg_kernel(const int* __restrict__ qidx, int* __restrict__ deg, int E) {
    int e = blockIdx.x * blockDim.x + threadIdx.x;
    if (e < E) atomicAdd(&deg[qidx[e]], 1);
}

// multi-block exclusive scan: phase 1 — per-block scan + block totals
__global__ void scan_block(const int* __restrict__ deg, int* __restrict__ offs,
                           int* __restrict__ bsum, int n) {
    __shared__ int ws[17];
    const int tid = threadIdx.x;              // 1024
    const int lane = tid & 63, wv = tid >> 6;
    int i = blockIdx.x * 1024 + tid;
    int v = (i < n) ? deg[i] : 0;
    int sc = v;
    #pragma unroll
    for (int d = 1; d < 64; d <<= 1) {
        int t = __shfl_up(sc, d, 64);
        if (lane >= d) sc += t;
    }
    if (lane == 63) ws[wv] = sc;
    __syncthreads();
    if (tid == 0) {
        int base = 0;
        #pragma unroll
        for (int w = 0; w < 16; ++w) { int t = ws[w]; ws[w] = base; base += t; }
        ws[16] = base;
    }
    __syncthreads();
    if (i < n) offs[i] = ws[wv] + (sc - v);
    if (tid == 0) bsum[blockIdx.x] = ws[16];
}

// phase 2 — exclusive scan of block totals (nb <= 64 fast path; serial fallback)
__global__ void scan_tops(int* __restrict__ bsum, int nb) {
    if (nb <= 64) {
        int lane = threadIdx.x;
        int v = (lane < nb) ? bsum[lane] : 0;
        int sc = v;
        #pragma unroll
        for (int d = 1; d < 64; d <<= 1) {
            int t = __shfl_up(sc, d, 64);
            if (lane >= d) sc += t;
        }
        if (lane < nb) bsum[lane] = sc - v;
    } else if (threadIdx.x == 0) {
        int base = 0;
        for (int i = 0; i < nb; ++i) { int t = bsum[i]; bsum[i] = base; base += t; }
    }
}

// phase 3 — add block bases; also write offs[n] = E
__global__ void scan_add(const int* __restrict__ bsum, int* __restrict__ offs,
                         int n, int E) {
    int i = blockIdx.x * blockDim.x + threadIdx.x;
    if (i < n) offs[i] += bsum[i >> 10];
    if (i == 0) offs[n] = E;
}

// scatter SRC NODE IDS (not edge ids) into CSR buckets
__global__ void fill_kernel(const int* __restrict__ qidx, const int* __restrict__ kidx,
                            const int* __restrict__ offs, int* __restrict__ cursor,
                            int* __restrict__ srcl, int E) {
    int e = blockIdx.x * blockDim.x + threadIdx.x;
    if (e < E) {
        int d = qidx[e];
        int pos = offs[d] + atomicAdd(&cursor[d], 1);
        srcl[pos] = kidx[e];
    }
}

// ---------------------------------------------------------------------------
// Aggregation: one wave per destination node. Lane l owns dim pair (2l,2l+1);
// head a = l>>3; D=16 dot reduced via 3 shfl_xor within 8 lanes.
// Per edge: one uint2 (8B) load per lane from packed bf16 KV.
__global__ void agg_kernel(const float* __restrict__ Qn, const uint2* __restrict__ KV,
                           const int* __restrict__ offs, const int* __restrict__ srcl,
                           float* __restrict__ out, int n)
{
    const int lane = threadIdx.x & 63;
    const int wid  = threadIdx.x >> 6;
    const int node = blockIdx.x * 4 + wid;
    if (node >= n) return;

    const float2 qv = *(const float2*)&Qn[(size_t)node * HDIM + lane * 2];

    float acc0 = 0.f, acc1 = 0.f, dsum = 0.f;
    const int beg = offs[node], end = offs[node + 1];

#define EDGE_STEP(kv)                                                          \
    {                                                                          \
        float kx = __uint_as_float((kv).x << 16);                              \
        float ky = __uint_as_float((kv).x & 0xffff0000u);                      \
        float vx = __uint_as_float((kv).y << 16);                              \
        float vy = __uint_as_float((kv).y & 0xffff0000u);                      \
        float part = qv.x * kx + qv.y * ky;                                    \
        part += __shfl_xor(part, 1, 64);                                       \
        part += __shfl_xor(part, 2, 64);                                       \
        part += __shfl_xor(part, 4, 64);                                       \
        float w = __expf(part * 0.25f);                                        \
        dsum += w; acc0 += w * vx; acc1 += w * vy;                             \
    }

    for (int base = beg; base < end; base += 64) {
        int cnt = min(64, end - base);
        int my = (base + lane < end) ? srcl[base + lane] : 0;  // one vector load / 64 edges
        int j = 0;
        for (; j + 4 <= cnt; j += 4) {
            int s0 = __shfl(my, j,     64);
            int s1 = __shfl(my, j + 1, 64);
            int s2 = __shfl(my, j + 2, 64);
            int s3 = __shfl(my, j + 3, 64);
            uint2 k0 = KV[(size_t)s0 * 64 + lane];
            uint2 k1 = KV[(size_t)s1 * 64 + lane];
            uint2 k2 = KV[(size_t)s2 * 64 + lane];
            uint2 k3 = KV[(size_t)s3 * 64 + lane];
            EDGE_STEP(k0); EDGE_STEP(k1); EDGE_STEP(k2); EDGE_STEP(k3);
        }
        for (; j < cnt; ++j) {
            int s = __shfl(my, j, 64);
            uint2 kk = KV[(size_t)s * 64 + lane];
            EDGE_STEP(kk);
        }
    }
#undef EDGE_STEP

    float inv = 1.f / dsum;                   // deg>=1 (identity edges present)
    *(float2*)&out[(size_t)node * HDIM + lane * 2] = make_float2(acc0 * inv, acc1 * inv);
}

// ---------------------------------------------------------------------------
extern "C" void kernel_launch(void* const* d_in, const int* in_sizes, int n_in,
                              void* d_out, int out_size, void* d_ws, size_t ws_size,
                              hipStream_t stream) {
    const float* q  = (const float*)d_in[0];
    const float* k  = (const float*)d_in[1];
    const float* v  = (const float*)d_in[2];
    const float* Wq = (const float*)d_in[3];
    const float* bq = (const float*)d_in[4];
    const float* Wk = (const float*)d_in[5];
    const float* bk = (const float*)d_in[6];
    const float* Wv = (const float*)d_in[7];
    const float* bv = (const float*)d_in[8];
    const int* qidx = (const int*)d_in[9];
    const int* kidx = (const int*)d_in[10];
    float* out = (float*)d_out;

    const int N = in_sizes[0] / HDIM;
    const int E = in_sizes[9];

    char* p = (char*)d_ws;
    float*    Qn = (float*)p;    p += (size_t)N * HDIM * sizeof(float);
    unsigned* KV = (unsigned*)p; p += (size_t)N * HDIM * sizeof(unsigned); // packed bf16
    int* deg    = (int*)p; p += (size_t)N * sizeof(int);
    int* cursor = (int*)p; p += (size_t)N * sizeof(int);   // contiguous with deg
    int* offs   = (int*)p; p += (size_t)(N + 1) * sizeof(int);
    int* bsum   = (int*)p; p += 64 * sizeof(int);
    int* srcl   = (int*)p; p += (size_t)E * sizeof(int);

    const int nb = (N + 1023) / 1024;

    zero_kernel<<<(2 * N + 255) / 256, 256, 0, stream>>>(deg, 2 * N);
    {
        dim3 grid((N + 63) / 64, 3);
        proj_kernel<<<grid, 256, 0, stream>>>(q, k, v, Wq, bq, Wk, bk, Wv, bv,
                                              Qn, KV, N);
    }
    deg_kernel<<<(E + 255) / 256, 256, 0, stream>>>(qidx, deg, E);
    scan_block<<<nb, 1024, 0, stream>>>(deg, offs, bsum, N);
    scan_tops<<<1, 64, 0, stream>>>(bsum, nb);
    scan_add<<<(N + 1023) / 1024, 1024, 0, stream>>>(bsum, offs, N, E);
    fill_kernel<<<(E + 255) / 256, 256, 0, stream>>>(qidx, kidx, offs, cursor, srcl, E);
    agg_kernel<<<(N + 3) / 4, 256, 0, stream>>>(Qn, (const uint2*)KV, offs, srcl, out, N);
}

// Round 4
// 309.986 us; speedup vs baseline: 1.8550x; 1.4168x over previous
//
#include <hip/hip_runtime.h>
#include <hip/hip_bf16.h>

#define HDIM 128

typedef __attribute__((ext_vector_type(8))) short bf16x8;   // 8 bf16 in 4 VGPRs
typedef __attribute__((ext_vector_type(4))) float f32x4;

__device__ inline unsigned short f2bf(float f) {
    return __builtin_bit_cast(unsigned short, __float2bfloat16(f));
}

// ---------------------------------------------------------------------------
__global__ void zero_kernel(int* __restrict__ p, int n) {
    int i = blockIdx.x * blockDim.x + threadIdx.x;
    if (i < n) p[i] = 0;
}

// convert 3 fp32 W matrices (128x128 each) to bf16, concatenated
__global__ void cvtW_kernel(const float* __restrict__ Wq, const float* __restrict__ Wk,
                            const float* __restrict__ Wv, unsigned short* __restrict__ Wb) {
    int i = blockIdx.x * 256 + threadIdx.x;          // 0..49151
    int m = i >> 14, j = i & 16383;
    const float* W = (m == 0) ? Wq : (m == 1) ? Wk : Wv;
    Wb[i] = f2bf(W[j]);
}

// ---------------------------------------------------------------------------
// MFMA projection. gridDim = (ceil(N/64), 3); 256 thr = 4 waves; wave = 16 nodes.
// No LDS, no barriers. A = x rows (fp32->bf16 in-reg), B = Wb rows (bf16).
// Outputs: m=0 -> Qb bf16 [N][128]; m=1/2 -> K/V into interleaved KV uints:
//   ushort index = node*256 + 4*(c>>1) + 2*sel + (c&1)   (sel 0=K, 1=V)
// so agg's uint2 load {K2p|K2p+1, V2p|V2p+1} layout is preserved.
__global__ __launch_bounds__(256, 4)
void proj_mfma(const float* __restrict__ qin, const float* __restrict__ kin,
               const float* __restrict__ vin, const unsigned short* __restrict__ Wb,
               const float* __restrict__ bq, const float* __restrict__ bk,
               const float* __restrict__ bv,
               unsigned short* __restrict__ Qb, unsigned short* __restrict__ KVu, int n)
{
    const int lane = threadIdx.x & 63;
    const int wv   = threadIdx.x >> 6;
    const int m    = blockIdx.y;
    const long node0 = (long)blockIdx.x * 64 + wv * 16;
    if (node0 >= n) return;

    const float* x = (m == 0) ? qin : (m == 1) ? kin : vin;
    const short* W = (const short*)(Wb + (size_t)m * HDIM * HDIM);
    const float* b = (m == 0) ? bq  : (m == 1) ? bk  : bv;

    const int row  = lane & 15;          // A: node row; B: out col; D: out col
    const int quad = lane >> 4;

    // A fragments: 4 k-steps, 8 contiguous fp32 -> bf16x8 per lane
    bf16x8 af[4];
    const float* xrow = x + (size_t)(node0 + row) * HDIM + quad * 8;
    const bool rv = (node0 + row) < n;
    #pragma unroll
    for (int ks = 0; ks < 4; ++ks) {
        float4 lo = make_float4(0.f, 0.f, 0.f, 0.f);
        float4 hi = lo;
        if (rv) {
            lo = *(const float4*)(xrow + ks * 32);
            hi = *(const float4*)(xrow + ks * 32 + 4);
        }
        bf16x8 t;
        t[0] = (short)f2bf(lo.x); t[1] = (short)f2bf(lo.y);
        t[2] = (short)f2bf(lo.z); t[3] = (short)f2bf(lo.w);
        t[4] = (short)f2bf(hi.x); t[5] = (short)f2bf(hi.y);
        t[6] = (short)f2bf(hi.z); t[7] = (short)f2bf(hi.w);
        af[ks] = t;
    }

    #pragma unroll
    for (int nt = 0; nt < 8; ++nt) {
        f32x4 acc = {0.f, 0.f, 0.f, 0.f};
        // B frags: row (nt*16+row) of W, k = ks*32 + quad*8 .. +7 (contiguous bf16)
        const bf16x8* wr = (const bf16x8*)(W + (size_t)(nt * 16 + row) * HDIM + quad * 8);
        acc = __builtin_amdgcn_mfma_f32_16x16x32_bf16(af[0], wr[0],  acc, 0, 0, 0);
        acc = __builtin_amdgcn_mfma_f32_16x16x32_bf16(af[1], wr[4],  acc, 0, 0, 0);
        acc = __builtin_amdgcn_mfma_f32_16x16x32_bf16(af[2], wr[8],  acc, 0, 0, 0);
        acc = __builtin_amdgcn_mfma_f32_16x16x32_bf16(af[3], wr[12], acc, 0, 0, 0);

        const int c = nt * 16 + row;                 // output column
        const float bias = b[c];
        #pragma unroll
        for (int r = 0; r < 4; ++r) {
            long node = node0 + quad * 4 + r;        // D row = node within tile
            if (node < n) {
                unsigned short hv = f2bf(acc[r] + bias);
                if (m == 0) {
                    Qb[(size_t)node * HDIM + c] = hv;
                } else {
                    int sel = m - 1;
                    KVu[(size_t)node * 256 + 4 * (c >> 1) + 2 * sel + (c & 1)] = hv;
                }
            }
        }
    }
}

// ---------------------------------------------------------------------------
__global__ void deg_kernel(const int* __restrict__ qidx, int* __restrict__ deg, int E) {
    int e = blockIdx.x * blockDim.x + threadIdx.x;
    if (e < E) atomicAdd(&deg[qidx[e]], 1);
}

// multi-block exclusive scan: phase 1 — per-block scan + block totals
__global__ void scan_block(const int* __restrict__ deg, int* __restrict__ offs,
                           int* __restrict__ bsum, int n) {
    __shared__ int ws[17];
    const int tid = threadIdx.x;              // 1024
    const int lane = tid & 63, wv = tid >> 6;
    int i = blockIdx.x * 1024 + tid;
    int v = (i < n) ? deg[i] : 0;
    int sc = v;
    #pragma unroll
    for (int d = 1; d < 64; d <<= 1) {
        int t = __shfl_up(sc, d, 64);
        if (lane >= d) sc += t;
    }
    if (lane == 63) ws[wv] = sc;
    __syncthreads();
    if (tid == 0) {
        int base = 0;
        #pragma unroll
        for (int w = 0; w < 16; ++w) { int t = ws[w]; ws[w] = base; base += t; }
        ws[16] = base;
    }
    __syncthreads();
    if (i < n) offs[i] = ws[wv] + (sc - v);
    if (tid == 0) bsum[blockIdx.x] = ws[16];
}

// phase 2 — exclusive scan of block totals (nb <= 64 fast path)
__global__ void scan_tops(int* __restrict__ bsum, int nb) {
    if (nb <= 64) {
        int lane = threadIdx.x;
        int v = (lane < nb) ? bsum[lane] : 0;
        int sc = v;
        #pragma unroll
        for (int d = 1; d < 64; d <<= 1) {
            int t = __shfl_up(sc, d, 64);
            if (lane >= d) sc += t;
        }
        if (lane < nb) bsum[lane] = sc - v;
    } else if (threadIdx.x == 0) {
        int base = 0;
        for (int i = 0; i < nb; ++i) { int t = bsum[i]; bsum[i] = base; base += t; }
    }
}

// phase 3 — add block bases; also write offs[n] = E
__global__ void scan_add(const int* __restrict__ bsum, int* __restrict__ offs,
                         int n, int E) {
    int i = blockIdx.x * blockDim.x + threadIdx.x;
    if (i < n) offs[i] += bsum[i >> 10];
    if (i == 0) offs[n] = E;
}

// scatter SRC NODE IDS into CSR buckets
__global__ void fill_kernel(const int* __restrict__ qidx, const int* __restrict__ kidx,
                            const int* __restrict__ offs, int* __restrict__ cursor,
                            int* __restrict__ srcl, int E) {
    int e = blockIdx.x * blockDim.x + threadIdx.x;
    if (e < E) {
        int d = qidx[e];
        int pos = offs[d] + atomicAdd(&cursor[d], 1);
        srcl[pos] = kidx[e];
    }
}

// ---------------------------------------------------------------------------
// Aggregation: one wave per destination node. Lane l owns dim pair (2l,2l+1);
// head a = l>>3; D=16 dot reduced via 3 shfl_xor within 8 lanes.
// Q is bf16 (uint = 2 dims); per edge one uint2 (8B) load from packed bf16 KV.
__global__ void agg_kernel(const unsigned* __restrict__ Qu, const uint2* __restrict__ KV,
                           const int* __restrict__ offs, const int* __restrict__ srcl,
                           float* __restrict__ out, int n)
{
    const int lane = threadIdx.x & 63;
    const int wid  = threadIdx.x >> 6;
    const int node = blockIdx.x * 4 + wid;
    if (node >= n) return;

    unsigned qu = Qu[(size_t)node * 64 + lane];
    const float qx = __uint_as_float(qu << 16);
    const float qy = __uint_as_float(qu & 0xffff0000u);

    float acc0 = 0.f, acc1 = 0.f, dsum = 0.f;
    const int beg = offs[node], end = offs[node + 1];

#define EDGE_STEP(kv)                                                          \
    {                                                                          \
        float kx = __uint_as_float((kv).x << 16);                              \
        float ky = __uint_as_float((kv).x & 0xffff0000u);                      \
        float vx = __uint_as_float((kv).y << 16);                              \
        float vy = __uint_as_float((kv).y & 0xffff0000u);                      \
        float part = qx * kx + qy * ky;                                        \
        part += __shfl_xor(part, 1, 64);                                       \
        part += __shfl_xor(part, 2, 64);                                       \
        part += __shfl_xor(part, 4, 64);                                       \
        float w = __expf(part * 0.25f);                                        \
        dsum += w; acc0 += w * vx; acc1 += w * vy;                             \
    }

    for (int base = beg; base < end; base += 64) {
        int cnt = min(64, end - base);
        int my = (base + lane < end) ? srcl[base + lane] : 0;
        int j = 0;
        for (; j + 4 <= cnt; j += 4) {
            int s0 = __shfl(my, j,     64);
            int s1 = __shfl(my, j + 1, 64);
            int s2 = __shfl(my, j + 2, 64);
            int s3 = __shfl(my, j + 3, 64);
            uint2 k0 = KV[(size_t)s0 * 64 + lane];
            uint2 k1 = KV[(size_t)s1 * 64 + lane];
            uint2 k2 = KV[(size_t)s2 * 64 + lane];
            uint2 k3 = KV[(size_t)s3 * 64 + lane];
            EDGE_STEP(k0); EDGE_STEP(k1); EDGE_STEP(k2); EDGE_STEP(k3);
        }
        for (; j < cnt; ++j) {
            int s = __shfl(my, j, 64);
            uint2 kk = KV[(size_t)s * 64 + lane];
            EDGE_STEP(kk);
        }
    }
#undef EDGE_STEP

    float inv = 1.f / dsum;                   // deg>=1 (identity edges present)
    *(float2*)&out[(size_t)node * HDIM + lane * 2] = make_float2(acc0 * inv, acc1 * inv);
}

// ---------------------------------------------------------------------------
extern "C" void kernel_launch(void* const* d_in, const int* in_sizes, int n_in,
                              void* d_out, int out_size, void* d_ws, size_t ws_size,
                              hipStream_t stream) {
    const float* q  = (const float*)d_in[0];
    const float* k  = (const float*)d_in[1];
    const float* v  = (const float*)d_in[2];
    const float* Wq = (const float*)d_in[3];
    const float* bq = (const float*)d_in[4];
    const float* Wk = (const float*)d_in[5];
    const float* bk = (const float*)d_in[6];
    const float* Wv = (const float*)d_in[7];
    const float* bv = (const float*)d_in[8];
    const int* qidx = (const int*)d_in[9];
    const int* kidx = (const int*)d_in[10];
    float* out = (float*)d_out;

    const int N = in_sizes[0] / HDIM;
    const int E = in_sizes[9];

    char* p = (char*)d_ws;
    unsigned short* Qb = (unsigned short*)p; p += (size_t)N * HDIM * sizeof(unsigned short);
    unsigned*       KV = (unsigned*)p;       p += (size_t)N * HDIM * sizeof(unsigned);
    unsigned short* Wb = (unsigned short*)p; p += (size_t)3 * HDIM * HDIM * sizeof(unsigned short);
    int* deg    = (int*)p; p += (size_t)N * sizeof(int);
    int* cursor = (int*)p; p += (size_t)N * sizeof(int);   // contiguous with deg
    int* offs   = (int*)p; p += (size_t)(N + 1) * sizeof(int);
    int* bsum   = (int*)p; p += 64 * sizeof(int);
    int* srcl   = (int*)p; p += (size_t)E * sizeof(int);

    const int nb = (N + 1023) / 1024;

    zero_kernel<<<(2 * N + 255) / 256, 256, 0, stream>>>(deg, 2 * N);
    cvtW_kernel<<<192, 256, 0, stream>>>(Wq, Wk, Wv, Wb);
    {
        dim3 grid((N + 63) / 64, 3);
        proj_mfma<<<grid, 256, 0, stream>>>(q, k, v, Wb, bq, bk, bv,
                                            Qb, (unsigned short*)KV, N);
    }
    deg_kernel<<<(E + 255) / 256, 256, 0, stream>>>(qidx, deg, E);
    scan_block<<<nb, 1024, 0, stream>>>(deg, offs, bsum, N);
    scan_tops<<<1, 64, 0, stream>>>(bsum, nb);
    scan_add<<<(N + 1023) / 1024, 1024, 0, stream>>>(bsum, offs, N, E);
    fill_kernel<<<(E + 255) / 256, 256, 0, stream>>>(qidx, kidx, offs, cursor, srcl, E);
    agg_kernel<<<(N + 3) / 4, 256, 0, stream>>>((const unsigned*)Qb, (const uint2*)KV,
                                                offs, srcl, out, N);
}